// Round 19
// baseline (98.868 us; speedup 1.0000x reference)
//
#include <hip/hip_runtime.h>

typedef __attribute__((ext_vector_type(8))) short short8;   // 8 bf16 (MFMA A/B frag)
typedef __attribute__((ext_vector_type(4))) float f32x4;
typedef __attribute__((ext_vector_type(4))) int   i32x4;

#define SDIM 32
#define HDIM 34
#define NEXP 12
#define ACOL 256
#define SPB  256
#define MAXROWS 640        // 32-granular padding: worst = 256 + 12*31 = 628
#define STGS 260           // bf16 staging stride (ushorts), 32 rows

// raw barrier: waits LDS ops only, never drains global stores (T4)
#define BAR_LGKM() asm volatile("s_waitcnt lgkmcnt(0)\n\ts_barrier" ::: "memory")

// fp32 -> bf16 (round-to-nearest-ish), pack two into one dword
__device__ __forceinline__ unsigned int bpack(float lo, float hi) {
    unsigned int a = __builtin_bit_cast(unsigned int, lo);
    unsigned int b = __builtin_bit_cast(unsigned int, hi);
    return ((a + 0x8000u) >> 16) | ((b + 0x8000u) & 0xffff0000u);
}

// ---- k0: pack Wout into fragment-ordered bf16 records (R13 layout) ----
// wpack[((e*4+wv)*4+j)*64 + lane] = 8 bf16 of W[col=wv*64+j*16+(lane&15)][k=8g..8g+7]
__global__ __launch_bounds__(256) void k0_wpack(
    const float* __restrict__ Wout, uint4* __restrict__ wpack,
    unsigned int* __restrict__ w2p)
{
    const int tid = blockIdx.x * 256 + threadIdx.x;
    if (tid >= NEXP * 4 * 4 * 64) return;
    const int lane = tid & 63;
    const int j    = (tid >> 6) & 3;
    const int wvv  = (tid >> 8) & 3;
    const int e    = tid >> 10;
    const int r = lane & 15, g = lane >> 4;
    const int col = wvv * 64 + j * 16 + r;
    const float* wr = Wout + ((size_t)e * ACOL + col) * HDIM;
    uint4 q;
    q.x = bpack(wr[g*8+0], wr[g*8+1]);
    q.y = bpack(wr[g*8+2], wr[g*8+3]);
    q.z = bpack(wr[g*8+4], wr[g*8+5]);
    q.w = bpack(wr[g*8+6], wr[g*8+7]);
    wpack[tid] = q;
    if (tid < NEXP * ACOL) {                       // w2: k=32,33 per (e,col)
        const float* wr2 = Wout + (size_t)tid * HDIM;
        w2p[tid] = bpack(wr2[32], wr2[33]);
    }
}

__global__ __launch_bounds__(256, 2) void actor_kernel(
    const float* __restrict__ states,
    const int*   __restrict__ epoch_idx,
    const float* __restrict__ W1,
    const float* __restrict__ b1,
    const uint4* __restrict__ wpack,
    const unsigned int* __restrict__ w2p,
    const float* __restrict__ bout,
    const int*   __restrict__ mask,
    float*       __restrict__ out,
    int nB)
{
    // xs: 64 B/row = bf16 k0..31 in 4 16B chunks, chunk c at (c ^ ((row>>2)&3)).
    __shared__ __align__(16) unsigned int xs[MAXROWS * 16];      // 40960 B
    __shared__ unsigned int   xt[MAXROWS];                       // 2560 B (k32,33)
    __shared__ unsigned short rowid[MAXROWS];                    // 1280 B
    __shared__ __align__(8) unsigned short stgb[32 * STGS];      // 16640 B bf16 staging
    __shared__ int cnt[NEXP], goff[NEXP], ntl[NEXP];
    // total ~61.6 KB -> 2 blocks/CU

    float* w1s = (float*)stgb;           // aliased: phases 0-1 only (4488 B)
    float* b1s = w1s + HDIM * SDIM;

    const int t  = threadIdx.x;
    const int s0 = blockIdx.x * SPB;

    // ---- phase 0 ----
    for (int i = t; i < HDIM * SDIM; i += 256) w1s[i] = W1[i];
    if (t < HDIM) b1s[t] = b1[t];
    if (t < NEXP) cnt[t] = 0;
    for (int i = t; i < MAXROWS; i += 256) rowid[i] = 0xFFFFu;

    const int  sidx  = s0 + t;
    const bool valid = (sidx < nB);
    float sr[SDIM];
    int e = 0;
    if (valid) {
        const f32x4* sp = (const f32x4*)(states + (size_t)sidx * SDIM);
        #pragma unroll
        for (int q = 0; q < SDIM / 4; ++q) {
            f32x4 v = sp[q];
            sr[4*q+0] = v[0]; sr[4*q+1] = v[1]; sr[4*q+2] = v[2]; sr[4*q+3] = v[3];
        }
        e = epoch_idx[sidx];
    }
    __syncthreads();                 // cnt zeroed, w1s staged

    int rank = 0;
    if (valid) rank = atomicAdd(&cnt[e], 1);
    __syncthreads();                 // cnt final

    if (t == 0) {
        int base = 0;
        #pragma unroll
        for (int i = 0; i < NEXP; ++i) {
            goff[i] = base;
            int nt = (cnt[i] + 31) >> 5;       // 32-row tiles
            ntl[i] = nt;
            base += nt << 5;
        }
    }
    float x[HDIM];
    if (valid) {
        #pragma unroll 2
        for (int h = 0; h < HDIM; ++h) {
            float acc = b1s[h];
            const float4* wr = (const float4*)(w1s + h * SDIM);
            #pragma unroll
            for (int q = 0; q < SDIM / 4; ++q) {
                float4 wv = wr[q];
                acc = fmaf(sr[4*q+0], wv.x, acc);
                acc = fmaf(sr[4*q+1], wv.y, acc);
                acc = fmaf(sr[4*q+2], wv.z, acc);
                acc = fmaf(sr[4*q+3], wv.w, acc);
            }
            x[h] = fmaxf(acc, 0.0f);
        }
    }
    __syncthreads();                 // goff ready; w1s reads done

    // ---- phase 2: scatter bf16 x row into sorted+padded slot (swizzled) ----
    if (valid) {
        const int slot = goff[e] + rank;
        const unsigned sw = (((unsigned)slot >> 2) & 3u) << 4;
        char* rbase = (char*)xs + slot * 64;
        unsigned d[17];
        #pragma unroll
        for (int k = 0; k < 17; ++k) d[k] = bpack(x[2*k], x[2*k+1]);
        #pragma unroll
        for (int c = 0; c < 4; ++c) {
            f32x4 q;
            q[0] = __builtin_bit_cast(float, d[4*c+0]);
            q[1] = __builtin_bit_cast(float, d[4*c+1]);
            q[2] = __builtin_bit_cast(float, d[4*c+2]);
            q[3] = __builtin_bit_cast(float, d[4*c+3]);
            *(f32x4*)(rbase + (((unsigned)(c * 16)) ^ sw)) = q;
        }
        xt[slot]    = bpack(x[32], x[33]);
        rowid[slot] = (unsigned short)t;
    }
    __syncthreads();                 // xs/xt/rowid visible

    // ---- phase 3: 32-row tiles; 16 MFMAs + staged transpose; 2 barriers/tile ----
    const int wv   = t >> 6;
    const int lane = t & 63;
    const int r    = lane & 15;
    const int g    = lane >> 4;
    const int colbase = wv * 64 + r;
    const float NEG = -1e9f;
    const i32x4 mq = *(const i32x4*)(mask + 4 * lane);

    float* outb = out + (size_t)s0 * ACOL;

    for (int e2 = 0; e2 < NEXP; ++e2) {
        const int ntiles = ntl[e2];
        if (ntiles == 0) continue;

        // coalesced W fragments + per-lane store-side bias
        short8   bf1[4];
        unsigned w2[4];
        const uint4* wp = wpack + ((size_t)(e2 * 4 + wv) * 4) * 64 + lane;
        #pragma unroll
        for (int j = 0; j < 4; ++j) {
            bf1[j] = __builtin_bit_cast(short8, wp[j * 64]);
            w2[j]  = (g == 0) ? w2p[e2 * ACOL + colbase + j * 16] : 0u;
        }
        const f32x4 bias4 = *(const f32x4*)(bout + e2 * ACOL + 4 * lane);

        const int tb = goff[e2];
        for (int st = 0; st < ntiles; ++st) {
            const int rb = tb + (st << 5);
            // two 16-row MFMA groups: rows rb+r and rb+16+r
            const int rowA = rb + r, rowB = rb + 16 + r;
            const unsigned swA = (((unsigned)rowA >> 2) & 3u) << 4;
            const unsigned swB = (((unsigned)rowB >> 2) & 3u) << 4;
            short8 a1A = *(const short8*)((const char*)xs + rowA * 64 +
                                          (((unsigned)(g * 16)) ^ swA));
            short8 a1B = *(const short8*)((const char*)xs + rowB * 64 +
                                          (((unsigned)(g * 16)) ^ swB));
            short8 a2A = __builtin_bit_cast(short8,
                           make_uint4(g == 0 ? xt[rowA] : 0u, 0u, 0u, 0u));
            short8 a2B = __builtin_bit_cast(short8,
                           make_uint4(g == 0 ? xt[rowB] : 0u, 0u, 0u, 0u));

            f32x4 accA[4], accB[4];
            #pragma unroll
            for (int j = 0; j < 4; ++j) {
                short8 b2 = __builtin_bit_cast(short8,
                              make_uint4(w2[j], 0u, 0u, 0u));
                f32x4 a = {0.f, 0.f, 0.f, 0.f};
                a = __builtin_amdgcn_mfma_f32_16x16x32_bf16(a1A, bf1[j], a, 0, 0, 0);
                a = __builtin_amdgcn_mfma_f32_16x16x32_bf16(a2A, b2, a, 0, 0, 0);
                accA[j] = a;
                f32x4 b = {0.f, 0.f, 0.f, 0.f};
                b = __builtin_amdgcn_mfma_f32_16x16x32_bf16(a1B, bf1[j], b, 0, 0, 0);
                b = __builtin_amdgcn_mfma_f32_16x16x32_bf16(a2B, b2, b, 0, 0, 0);
                accB[j] = b;
            }

            BAR_LGKM();   // WAR: all waves' reads of previous tile's stgb done

            #pragma unroll
            for (int j = 0; j < 4; ++j) {
                const int c = colbase + 16 * j;
                #pragma unroll
                for (int i = 0; i < 4; ++i) {
                    stgb[(g * 4 + i) * STGS + c] =
                        (unsigned short)bpack(accA[j][i], 0.0f);
                    stgb[(16 + g * 4 + i) * STGS + c] =
                        (unsigned short)bpack(accB[j][i], 0.0f);
                }
            }

            BAR_LGKM();   // RAW: staging visible

            // wave stores 8 full 1KB rows: bf16->f32 + bias + mask, plain dwordx4
            #pragma unroll
            for (int q = 0; q < 8; ++q) {
                const int lrow = wv * 8 + q;
                const unsigned rid = rowid[rb + lrow];
                const uint2 du = *(const uint2*)&stgb[lrow * STGS + 4 * lane];
                f32x4 v;
                v[0] = __builtin_bit_cast(float, du.x << 16)         + bias4[0];
                v[1] = __builtin_bit_cast(float, du.x & 0xffff0000u) + bias4[1];
                v[2] = __builtin_bit_cast(float, du.y << 16)         + bias4[2];
                v[3] = __builtin_bit_cast(float, du.y & 0xffff0000u) + bias4[3];
                v[0] = mq[0] ? v[0] : NEG;
                v[1] = mq[1] ? v[1] : NEG;
                v[2] = mq[2] ? v[2] : NEG;
                v[3] = mq[3] ? v[3] : NEG;
                if (rid != 0xFFFFu)
                    *(f32x4*)(outb + (size_t)rid * ACOL + 4 * lane) = v;
            }
        }
    }
}

extern "C" void kernel_launch(void* const* d_in, const int* in_sizes, int n_in,
                              void* d_out, int out_size, void* d_ws, size_t ws_size,
                              hipStream_t stream) {
    const float* states    = (const float*)d_in[0];
    const int*   epoch_idx = (const int*)  d_in[1];
    const float* W1        = (const float*)d_in[2];
    const float* b1        = (const float*)d_in[3];
    const float* Wout      = (const float*)d_in[4];
    const float* bout      = (const float*)d_in[5];
    const int*   mask      = (const int*)  d_in[6];
    float*       out       = (float*)d_out;

    const int nB   = in_sizes[0] / SDIM;
    const int grid = (nB + SPB - 1) / SPB;

    uint4*        wpack = (uint4*)d_ws;                          // 196608 B
    unsigned int* w2p   = (unsigned int*)((char*)d_ws + 196608); // 12288 B

    k0_wpack<<<48, 256, 0, stream>>>(Wout, wpack, w2p);
    actor_kernel<<<grid, 256, 0, stream>>>(states, epoch_idx, W1, b1,
                                           wpack, w2p, bout, mask, out, nB);
}

// Round 20
// 87.388 us; speedup vs baseline: 1.1314x; 1.1314x over previous
//
#include <hip/hip_runtime.h>

typedef __attribute__((ext_vector_type(8))) short short8;   // 8 bf16 (MFMA A/B frag)
typedef __attribute__((ext_vector_type(4))) float f32x4;
typedef __attribute__((ext_vector_type(4))) int   i32x4;

#define SDIM 32
#define HDIM 34
#define NEXP 12
#define ACOL 256
#define SPB  256
#define MAXROWS 448        // max padded rows = 256 + 12*15 = 436
#define SLABS 264          // per-wave slab stride in ushorts (256 + 8)

// fp32 -> bf16 (round-to-nearest-ish), pack two into one dword
__device__ __forceinline__ unsigned int bpack(float lo, float hi) {
    unsigned int a = __builtin_bit_cast(unsigned int, lo);
    unsigned int b = __builtin_bit_cast(unsigned int, hi);
    return ((a + 0x8000u) >> 16) | ((b + 0x8000u) & 0xffff0000u);
}

// ---- k0: pack Wout fragment-ordered + {k32k33 | bias} records ----
// wpack[(e*16+j)*64 + lane] = 8 bf16 of W[col=16j+(lane&15)][k=8g..8g+7], g=lane>>4
// w2b[e*256+col] = { bf16(W[32],W[33]), bf16(bias, 0) }
__global__ __launch_bounds__(256) void k0_wpack(
    const float* __restrict__ Wout, const float* __restrict__ bout,
    uint4* __restrict__ wpack, uint2* __restrict__ w2b)
{
    const int tid = blockIdx.x * 256 + threadIdx.x;
    if (tid < NEXP * 16 * 64) {
        const int lane = tid & 63;
        const int j    = (tid >> 6) & 15;
        const int e    = tid >> 10;
        const int r = lane & 15, g = lane >> 4;
        const int col = j * 16 + r;
        const float* wr = Wout + ((size_t)e * ACOL + col) * HDIM;
        uint4 q;
        q.x = bpack(wr[g*8+0], wr[g*8+1]);
        q.y = bpack(wr[g*8+2], wr[g*8+3]);
        q.z = bpack(wr[g*8+4], wr[g*8+5]);
        q.w = bpack(wr[g*8+6], wr[g*8+7]);
        wpack[tid] = q;
    }
    if (tid < NEXP * ACOL) {
        const float* wr2 = Wout + (size_t)tid * HDIM;
        w2b[tid] = make_uint2(bpack(wr2[32], wr2[33]), bpack(bout[tid], 0.0f));
    }
}

__global__ __launch_bounds__(256, 2) void actor_kernel(
    const float* __restrict__ states,
    const int*   __restrict__ epoch_idx,
    const float* __restrict__ W1,
    const float* __restrict__ b1,
    const uint4* __restrict__ wpack,
    const uint2* __restrict__ w2b,
    const int*   __restrict__ mask,
    float*       __restrict__ out,
    int nB)
{
    // xs: 64 B/row = bf16 k0..31 in 4 16B chunks, chunk c at (c ^ ((row>>2)&3)).
    __shared__ __align__(16) unsigned int xs[MAXROWS * 16];      // 28672 B
    __shared__ uint2          xt2[MAXROWS];                      // 3584 B {x32x33, 1|0}
    __shared__ unsigned short lrid[MAXROWS];                     // 896 B
    __shared__ __align__(8) unsigned short slab[4][16 * SLABS];  // 33792 B private
    __shared__ int texp[32];
    __shared__ int cnt[NEXP], goff[NEXP], ntl[NEXP], ntt;
    // total ~67 KB -> 2 blocks/CU

    float* w1s = (float*)&slab[0][0];    // aliased: phases 0-1 only (4488 B)
    float* b1s = w1s + HDIM * SDIM;

    const int t  = threadIdx.x;
    const int s0 = blockIdx.x * SPB;

    // ---- phase 0 ----
    for (int i = t; i < HDIM * SDIM; i += 256) w1s[i] = W1[i];
    if (t < HDIM) b1s[t] = b1[t];
    if (t < NEXP) cnt[t] = 0;
    for (int i = t; i < MAXROWS; i += 256) lrid[i] = 0xFFFFu;

    const int  sidx  = s0 + t;
    const bool valid = (sidx < nB);
    float sr[SDIM];
    int e = 0;
    if (valid) {
        const f32x4* sp = (const f32x4*)(states + (size_t)sidx * SDIM);
        #pragma unroll
        for (int q = 0; q < SDIM / 4; ++q) {
            f32x4 v = sp[q];
            sr[4*q+0] = v[0]; sr[4*q+1] = v[1]; sr[4*q+2] = v[2]; sr[4*q+3] = v[3];
        }
        e = epoch_idx[sidx];
    }
    __syncthreads();                 // cnt zeroed, w1s staged

    int rank = 0;
    if (valid) rank = atomicAdd(&cnt[e], 1);
    __syncthreads();                 // cnt final

    if (t == 0) {
        int base = 0;
        #pragma unroll
        for (int i = 0; i < NEXP; ++i) {
            goff[i] = base;
            int nt = (cnt[i] + 15) >> 4;
            ntl[i] = nt;
            base += nt << 4;
        }
        ntt = base >> 4;
    }
    float x[HDIM];
    if (valid) {
        #pragma unroll 2
        for (int h = 0; h < HDIM; ++h) {
            float acc = b1s[h];
            const float4* wr = (const float4*)(w1s + h * SDIM);
            #pragma unroll
            for (int q = 0; q < SDIM / 4; ++q) {
                float4 wv4 = wr[q];
                acc = fmaf(sr[4*q+0], wv4.x, acc);
                acc = fmaf(sr[4*q+1], wv4.y, acc);
                acc = fmaf(sr[4*q+2], wv4.z, acc);
                acc = fmaf(sr[4*q+3], wv4.w, acc);
            }
            x[h] = fmaxf(acc, 0.0f);
        }
    }
    __syncthreads();                 // goff/ntl/ntt ready; w1s reads done

    if (t < NEXP) {                  // tile -> expert map
        const int tb0 = goff[t] >> 4;
        for (int k = 0; k < ntl[t]; ++k) texp[tb0 + k] = t;
    }
    // ---- phase 2: scatter bf16 x row into sorted+padded slot (swizzled) ----
    if (valid) {
        const int slot = goff[e] + rank;
        const unsigned sw = (((unsigned)slot >> 2) & 3u) << 4;
        char* rbase = (char*)xs + slot * 64;
        unsigned d[17];
        #pragma unroll
        for (int k = 0; k < 17; ++k) d[k] = bpack(x[2*k], x[2*k+1]);
        #pragma unroll
        for (int c = 0; c < 4; ++c) {
            f32x4 q;
            q[0] = __builtin_bit_cast(float, d[4*c+0]);
            q[1] = __builtin_bit_cast(float, d[4*c+1]);
            q[2] = __builtin_bit_cast(float, d[4*c+2]);
            q[3] = __builtin_bit_cast(float, d[4*c+3]);
            *(f32x4*)(rbase + (((unsigned)(c * 16)) ^ sw)) = q;
        }
        xt2[slot]  = make_uint2(d[16], bpack(1.0f, 0.0f));   // {x32,x33} | {1,0}
        lrid[slot] = (unsigned short)t;
    }
    __syncthreads();                 // xs/xt2/lrid/texp visible — LAST barrier

    // ---- phase 3: wave-independent contiguous tile chunks, zero barriers ----
    const int wv   = t >> 6;
    const int lane = t & 63;
    const int r    = lane & 15;      // state col (B) / W action-row sel (A)
    const int g    = lane >> 4;      // k-group; lane holds actions 16j+4g..+3
    const float NEG = -1e9f;
    const i32x4 mq = *(const i32x4*)(mask + 4 * lane);
    const short8 z8 = __builtin_bit_cast(short8, make_uint4(0u, 0u, 0u, 0u));
    unsigned short* myslab = slab[wv];
    float* outb = out + (size_t)s0 * ACOL;

    const int nt_tot = ntt;
    const int t0 = (nt_tot * wv) >> 2;       // contiguous chunk per wave
    const int t1 = (nt_tot * (wv + 1)) >> 2;

    int cur_e = -1;
    uint4 wf[16];                            // W frags for all 16 col-tiles
    uint2 wx[16];                            // {W32W33, bias} per col-tile (g==0)

    for (int tile = t0; tile < t1; ++tile) {
        const int e2 = texp[tile];
        if (e2 != cur_e) {                   // reload on expert-run boundary only
            cur_e = e2;
            const uint4* wp = wpack + (size_t)(e2 * 16) * 64 + lane;
            const uint2* wb = w2b + e2 * ACOL + r;
            #pragma unroll
            for (int j = 0; j < 16; ++j) {
                wf[j] = wp[j * 64];
                wx[j] = (g == 0) ? wb[j * 16] : make_uint2(0u, 0u);
            }
        }

        const int rb  = tile << 4;
        const int row = rb + r;
        const char* rp = (const char*)xs + row * 64;
        short8 bx = *(const short8*)(rp +
                      (((unsigned)(g * 16)) ^ ((((unsigned)row >> 2) & 3u) << 4)));
        const uint2 x2 = xt2[row];
        const short8 bxe = (g == 0)
            ? __builtin_bit_cast(short8, make_uint4(x2.x, x2.y, 0u, 0u)) : z8;

        // 16 col-tiles; lane -> actions 16j+4g..+3 of state r; 1 b64 write each
        #pragma unroll
        for (int j = 0; j < 16; ++j) {
            f32x4 a = {0.f, 0.f, 0.f, 0.f};
            a = __builtin_amdgcn_mfma_f32_16x16x32_bf16(
                    __builtin_bit_cast(short8, wf[j]), bx, a, 0, 0, 0);
            const short8 ax = __builtin_bit_cast(short8,
                                make_uint4(wx[j].x, wx[j].y, 0u, 0u));
            a = __builtin_amdgcn_mfma_f32_16x16x32_bf16(ax, bxe, a, 0, 0, 0);
            *(uint2*)(myslab + r * SLABS + 16 * j + 4 * g) =
                make_uint2(bpack(a[0], a[1]), bpack(a[2], a[3]));
        }

        // stream 16 full 1KB rows, back-to-back (intra-wave lgkm ordering only)
        #pragma unroll
        for (int lrow = 0; lrow < 16; ++lrow) {
            const unsigned rid = lrid[rb + lrow];
            const uint2 dv = *(const uint2*)(myslab + lrow * SLABS + 4 * lane);
            f32x4 v;
            v[0] = __builtin_bit_cast(float, dv.x << 16);
            v[1] = __builtin_bit_cast(float, dv.x & 0xffff0000u);
            v[2] = __builtin_bit_cast(float, dv.y << 16);
            v[3] = __builtin_bit_cast(float, dv.y & 0xffff0000u);
            v[0] = mq[0] ? v[0] : NEG;
            v[1] = mq[1] ? v[1] : NEG;
            v[2] = mq[2] ? v[2] : NEG;
            v[3] = mq[3] ? v[3] : NEG;
            if (rid != 0xFFFFu)
                *(f32x4*)(outb + (size_t)rid * ACOL + 4 * lane) = v;
        }
    }
}

extern "C" void kernel_launch(void* const* d_in, const int* in_sizes, int n_in,
                              void* d_out, int out_size, void* d_ws, size_t ws_size,
                              hipStream_t stream) {
    const float* states    = (const float*)d_in[0];
    const int*   epoch_idx = (const int*)  d_in[1];
    const float* W1        = (const float*)d_in[2];
    const float* b1        = (const float*)d_in[3];
    const float* Wout      = (const float*)d_in[4];
    const float* bout      = (const float*)d_in[5];
    const int*   mask      = (const int*)  d_in[6];
    float*       out       = (float*)d_out;

    const int nB   = in_sizes[0] / SDIM;
    const int grid = (nB + SPB - 1) / SPB;

    uint4* wpack = (uint4*)d_ws;                                // 786432 B
    uint2* w2b   = (uint2*)((char*)d_ws + 786432);              // 24576 B

    k0_wpack<<<48, 256, 0, stream>>>(Wout, bout, wpack, w2b);
    actor_kernel<<<grid, 256, 0, stream>>>(states, epoch_idx, W1, b1,
                                           wpack, w2b, mask, out, nB);
}

// Round 21
// 85.122 us; speedup vs baseline: 1.1615x; 1.0266x over previous
//
#include <hip/hip_runtime.h>

typedef __attribute__((ext_vector_type(8))) short short8;   // 8 bf16 (MFMA A/B frag)
typedef __attribute__((ext_vector_type(4))) float f32x4;
typedef __attribute__((ext_vector_type(4))) int   i32x4;

#define SDIM 32
#define HDIM 34
#define NEXP 12
#define ACOL 256
#define SPB  256
#define MAXROWS 448        // max padded rows = 256 + 12*15 = 436, round up
#define STGS 260           // bf16 staging stride (ushorts)

// raw barrier: waits LDS ops only, never drains global stores (T4)
#define BAR_LGKM() asm volatile("s_waitcnt lgkmcnt(0)\n\ts_barrier" ::: "memory")

// fp32 -> bf16 (round-to-nearest-ish), pack two into one dword
__device__ __forceinline__ unsigned int bpack(float lo, float hi) {
    unsigned int a = __builtin_bit_cast(unsigned int, lo);
    unsigned int b = __builtin_bit_cast(unsigned int, hi);
    return ((a + 0x8000u) >> 16) | ((b + 0x8000u) & 0xffff0000u);
}

// ---- k0: pack Wout into fragment-ordered bf16 records ----
// wpack[((e*4+wv)*4+j)*64 + lane] = 8 bf16 of W[col=wv*64+j*16+(lane&15)][k=8g..8g+7]
__global__ __launch_bounds__(256) void k0_wpack(
    const float* __restrict__ Wout, uint4* __restrict__ wpack,
    unsigned int* __restrict__ w2p)
{
    const int tid = blockIdx.x * 256 + threadIdx.x;
    if (tid >= NEXP * 4 * 4 * 64) return;
    const int lane = tid & 63;
    const int j    = (tid >> 6) & 3;
    const int wvv  = (tid >> 8) & 3;
    const int e    = tid >> 10;
    const int r = lane & 15, g = lane >> 4;
    const int col = wvv * 64 + j * 16 + r;
    const float* wr = Wout + ((size_t)e * ACOL + col) * HDIM;
    uint4 q;
    q.x = bpack(wr[g*8+0], wr[g*8+1]);
    q.y = bpack(wr[g*8+2], wr[g*8+3]);
    q.z = bpack(wr[g*8+4], wr[g*8+5]);
    q.w = bpack(wr[g*8+6], wr[g*8+7]);
    wpack[tid] = q;
    if (tid < NEXP * ACOL) {                       // w2: k=32,33 per (e,col)
        const float* wr2 = Wout + (size_t)tid * HDIM;
        w2p[tid] = bpack(wr2[32], wr2[33]);
    }
}

__global__ __launch_bounds__(256, 4) void actor_kernel(
    const float* __restrict__ states,
    const int*   __restrict__ epoch_idx,
    const float* __restrict__ W1,
    const float* __restrict__ b1,
    const uint4* __restrict__ wpack,
    const unsigned int* __restrict__ w2p,
    const float* __restrict__ bout,
    const int*   __restrict__ mask,
    float*       __restrict__ out,
    int nB)
{
    // xs: 64 B/row = bf16 k0..31 in 4 16B chunks, chunk c at (c ^ ((row>>2)&3)).
    __shared__ __align__(16) unsigned int xs[MAXROWS * 16];      // 28672 B
    __shared__ unsigned int   xt[MAXROWS];                       // 1792 B (k32,33)
    __shared__ unsigned short rowid[MAXROWS];                    // 896 B
    __shared__ __align__(8) unsigned short stgb[16 * STGS];      // 8320 B bf16 staging
    __shared__ int cnt[NEXP], goff[NEXP], ntl[NEXP];
    // total ~39.9 KB -> 4 blocks/CU (16 waves)

    float* w1s = (float*)stgb;           // aliased: phases 0-1 only (4488 B)
    float* b1s = w1s + HDIM * SDIM;

    const int t  = threadIdx.x;
    const int s0 = blockIdx.x * SPB;

    // ---- phase 0 ----
    for (int i = t; i < HDIM * SDIM; i += 256) w1s[i] = W1[i];
    if (t < HDIM) b1s[t] = b1[t];
    if (t < NEXP) cnt[t] = 0;
    for (int i = t; i < MAXROWS; i += 256) rowid[i] = 0xFFFFu;

    const int  sidx  = s0 + t;
    const bool valid = (sidx < nB);
    float sr[SDIM];
    int e = 0;
    if (valid) {
        const f32x4* sp = (const f32x4*)(states + (size_t)sidx * SDIM);
        #pragma unroll
        for (int q = 0; q < SDIM / 4; ++q) {
            f32x4 v = sp[q];
            sr[4*q+0] = v[0]; sr[4*q+1] = v[1]; sr[4*q+2] = v[2]; sr[4*q+3] = v[3];
        }
        e = epoch_idx[sidx];
    }
    __syncthreads();                 // cnt zeroed, w1s staged

    int rank = 0;
    if (valid) rank = atomicAdd(&cnt[e], 1);
    __syncthreads();                 // cnt final

    if (t == 0) {
        int base = 0;
        #pragma unroll
        for (int i = 0; i < NEXP; ++i) {
            goff[i] = base;
            int nt = (cnt[i] + 15) >> 4;
            ntl[i] = nt;
            base += nt << 4;
        }
    }
    float x[HDIM];
    if (valid) {
        #pragma unroll 2
        for (int h = 0; h < HDIM; ++h) {
            float acc = b1s[h];
            const float4* wr = (const float4*)(w1s + h * SDIM);
            #pragma unroll
            for (int q = 0; q < SDIM / 4; ++q) {
                float4 wv = wr[q];
                acc = fmaf(sr[4*q+0], wv.x, acc);
                acc = fmaf(sr[4*q+1], wv.y, acc);
                acc = fmaf(sr[4*q+2], wv.z, acc);
                acc = fmaf(sr[4*q+3], wv.w, acc);
            }
            x[h] = fmaxf(acc, 0.0f);
        }
    }
    __syncthreads();                 // goff ready; w1s reads done

    // ---- phase 2: scatter bf16 x row into sorted+padded slot (swizzled) ----
    if (valid) {
        const int slot = goff[e] + rank;
        const unsigned sw = (((unsigned)slot >> 2) & 3u) << 4;
        char* rbase = (char*)xs + slot * 64;
        unsigned d[17];
        #pragma unroll
        for (int k = 0; k < 17; ++k) d[k] = bpack(x[2*k], x[2*k+1]);
        #pragma unroll
        for (int c = 0; c < 4; ++c) {
            f32x4 q;
            q[0] = __builtin_bit_cast(float, d[4*c+0]);
            q[1] = __builtin_bit_cast(float, d[4*c+1]);
            q[2] = __builtin_bit_cast(float, d[4*c+2]);
            q[3] = __builtin_bit_cast(float, d[4*c+3]);
            *(f32x4*)(rbase + (((unsigned)(c * 16)) ^ sw)) = q;
        }
        xt[slot]    = bpack(x[32], x[33]);
        rowid[slot] = (unsigned short)t;
    }
    __syncthreads();                 // xs/xt/rowid visible

    // ---- phase 3: MFMA + bf16 staged transpose; 2 lgkm barriers/tile ----
    const int wv   = t >> 6;
    const int lane = t & 63;
    const int r    = lane & 15;
    const int g    = lane >> 4;
    const int colbase = wv * 64 + r;
    const float NEG = -1e9f;
    const i32x4 mq = *(const i32x4*)(mask + 4 * lane);

    float* outb = out + (size_t)s0 * ACOL;

    for (int e2 = 0; e2 < NEXP; ++e2) {
        const int ntiles = ntl[e2];
        if (ntiles == 0) continue;

        // coalesced W fragments + per-lane store-side bias
        short8   bf1[4];
        unsigned w2[4];
        const uint4* wp = wpack + ((size_t)(e2 * 4 + wv) * 4) * 64 + lane;
        #pragma unroll
        for (int j = 0; j < 4; ++j) {
            bf1[j] = __builtin_bit_cast(short8, wp[j * 64]);
            w2[j]  = (g == 0) ? w2p[e2 * ACOL + colbase + j * 16] : 0u;
        }
        const f32x4 bias4 = *(const f32x4*)(bout + e2 * ACOL + 4 * lane);

        const int tb = goff[e2];
        for (int st = 0; st < ntiles; ++st) {
            const int rb  = tb + (st << 4);
            const int row = rb + r;
            const unsigned sw = (((unsigned)row >> 2) & 3u) << 4;
            const char* rp = (const char*)xs + row * 64;
            short8 a1 = *(const short8*)(rp + (((unsigned)(g * 16)) ^ sw));
            short8 a2 = __builtin_bit_cast(short8,
                          make_uint4(g == 0 ? xt[row] : 0u, 0u, 0u, 0u));

            f32x4 acc[4];
            #pragma unroll
            for (int j = 0; j < 4; ++j) {
                f32x4 a = {0.f, 0.f, 0.f, 0.f};
                a = __builtin_amdgcn_mfma_f32_16x16x32_bf16(a1, bf1[j], a, 0, 0, 0);
                short8 b2 = __builtin_bit_cast(short8,
                              make_uint4(w2[j], 0u, 0u, 0u));
                a = __builtin_amdgcn_mfma_f32_16x16x32_bf16(a2, b2, a, 0, 0, 0);
                acc[j] = a;
            }

            BAR_LGKM();   // WAR: all waves' reads of previous tile's stgb done

            #pragma unroll
            for (int j = 0; j < 4; ++j) {
                const int c = colbase + 16 * j;
                #pragma unroll
                for (int i = 0; i < 4; ++i)
                    stgb[(g * 4 + i) * STGS + c] =
                        (unsigned short)bpack(acc[j][i], 0.0f);
            }

            BAR_LGKM();   // RAW: staging visible

            // wave stores 4 full 1KB rows: bf16->f32 + bias + mask, plain dwordx4
            #pragma unroll
            for (int q = 0; q < 4; ++q) {
                const int lrow = wv * 4 + q;
                const unsigned rid = rowid[rb + lrow];
                const uint2 du = *(const uint2*)&stgb[lrow * STGS + 4 * lane];
                f32x4 v;
                v[0] = __builtin_bit_cast(float, du.x << 16)         + bias4[0];
                v[1] = __builtin_bit_cast(float, du.x & 0xffff0000u) + bias4[1];
                v[2] = __builtin_bit_cast(float, du.y << 16)         + bias4[2];
                v[3] = __builtin_bit_cast(float, du.y & 0xffff0000u) + bias4[3];
                v[0] = mq[0] ? v[0] : NEG;
                v[1] = mq[1] ? v[1] : NEG;
                v[2] = mq[2] ? v[2] : NEG;
                v[3] = mq[3] ? v[3] : NEG;
                if (rid != 0xFFFFu)
                    *(f32x4*)(outb + (size_t)rid * ACOL + 4 * lane) = v;
            }
        }
    }
}

extern "C" void kernel_launch(void* const* d_in, const int* in_sizes, int n_in,
                              void* d_out, int out_size, void* d_ws, size_t ws_size,
                              hipStream_t stream) {
    const float* states    = (const float*)d_in[0];
    const int*   epoch_idx = (const int*)  d_in[1];
    const float* W1        = (const float*)d_in[2];
    const float* b1        = (const float*)d_in[3];
    const float* Wout      = (const float*)d_in[4];
    const float* bout      = (const float*)d_in[5];
    const int*   mask      = (const int*)  d_in[6];
    float*       out       = (float*)d_out;

    const int nB   = in_sizes[0] / SDIM;
    const int grid = (nB + SPB - 1) / SPB;

    uint4*        wpack = (uint4*)d_ws;                          // 196608 B
    unsigned int* w2p   = (unsigned int*)((char*)d_ws + 196608); // 12288 B

    k0_wpack<<<48, 256, 0, stream>>>(Wout, wpack, w2p);
    actor_kernel<<<grid, 256, 0, stream>>>(states, epoch_idx, W1, b1,
                                           wpack, w2p, bout, mask, out, nB);
}